// Round 3
// baseline (612.338 us; speedup 1.0000x reference)
//
#include <hip/hip_runtime.h>
#include <cstdint>
#include <cstddef>

#define NN 50000
#define NE 800000

typedef _Float16 f16x8 __attribute__((ext_vector_type(8)));
typedef _Float16 f16x4 __attribute__((ext_vector_type(4)));
typedef float f32x4 __attribute__((ext_vector_type(4)));

// ---------------------------------------------------------------------------
// Edge-index dtype robustness (int64 vs int32 canonicalization)
// ---------------------------------------------------------------------------
__device__ __forceinline__ int edge_at(const void* e, int is32, long long i) {
    return is32 ? ((const int*)e)[i] : (int)((const long long*)e)[i];
}

__global__ __launch_bounds__(64) void zero_flag_k(int* flag) {
    if (threadIdx.x == 0) *flag = 0;
}

__global__ __launch_bounds__(256) void detect_k(const int* __restrict__ w, int* __restrict__ flag) {
    int i = blockIdx.x * 256 + threadIdx.x;   // 0..1023
    if (i < 1024 && w[2 * i + 1] != 0) atomicOr(flag, 1);
}

// ---------------------------------------------------------------------------
// Hadamard: X0 = qe*obj, written as fp16 hi/lo split pair
// ---------------------------------------------------------------------------
__global__ __launch_bounds__(256) void hadamard_k(const float4* __restrict__ a,
                                                  const float4* __restrict__ b,
                                                  _Float16* __restrict__ Xh,
                                                  _Float16* __restrict__ Xl, int n4) {
    int i = blockIdx.x * 256 + threadIdx.x;
    if (i >= n4) return;
    float4 x = a[i], y = b[i];
    float v[4] = { x.x * y.x, x.y * y.y, x.z * y.z, x.w * y.w };
    f16x4 hh, ll;
    #pragma unroll
    for (int j = 0; j < 4; ++j) {
        _Float16 h = (_Float16)v[j];
        hh[j] = h;
        ll[j] = (_Float16)(v[j] - (float)h);
    }
    *(f16x4*)&Xh[(size_t)i * 4] = hh;
    *(f16x4*)&Xl[(size_t)i * 4] = ll;
}

// ---------------------------------------------------------------------------
// Degree / CSR build
// ---------------------------------------------------------------------------
__global__ __launch_bounds__(256) void init_k(int* __restrict__ deg, int* __restrict__ cursor, int n) {
    int i = blockIdx.x * 256 + threadIdx.x;
    if (i < n) { deg[i] = 1; cursor[i] = 0; }   // self-loop
}

__global__ __launch_bounds__(256) void count_k(const void* __restrict__ edges,
                                               const int* __restrict__ flag,
                                               int* __restrict__ deg, int e) {
    int i = blockIdx.x * 256 + threadIdx.x;
    if (i < e) {
        int is32 = *flag;
        atomicAdd(&deg[edge_at(edges, is32, i)], 1);
    }
}

__global__ __launch_bounds__(256) void dinv_k(const int* __restrict__ deg, float* __restrict__ dinv, int n) {
    int i = blockIdx.x * 256 + threadIdx.x;
    if (i < n) dinv[i] = rsqrtf((float)deg[i]);
}

__global__ __launch_bounds__(1024) void scan_k(const int* __restrict__ deg, int* __restrict__ rp, int n) {
    __shared__ int s[1024];
    int t = threadIdx.x;
    int chunk = (n + 1023) / 1024;
    int lo = t * chunk;
    int hi = lo + chunk; if (hi > n) hi = n;
    int sum = 0;
    for (int i = lo; i < hi; ++i) sum += deg[i] - 1;
    s[t] = sum;
    __syncthreads();
    for (int off = 1; off < 1024; off <<= 1) {
        int val = (t >= off) ? s[t - off] : 0;
        __syncthreads();
        s[t] += val;
        __syncthreads();
    }
    int run = (t == 0) ? 0 : s[t - 1];
    for (int i = lo; i < hi; ++i) { rp[i] = run; run += deg[i] - 1; }
    if (t == 1023) rp[n] = s[1023];
}

__global__ __launch_bounds__(256) void scatter_k(const void* __restrict__ edges,
                                                 const int* __restrict__ flag,
                                                 const float* __restrict__ dinv,
                                                 const int* __restrict__ rp,
                                                 int* __restrict__ cursor,
                                                 int* __restrict__ col_s,
                                                 float* __restrict__ norm_s, int e) {
    int i = blockIdx.x * 256 + threadIdx.x;
    if (i < e) {
        int is32 = *flag;
        int r = edge_at(edges, is32, i);
        int c = edge_at(edges, is32, (long long)NE + i);
        int pos = rp[r] + atomicAdd(&cursor[r], 1);
        col_s[pos] = c;
        norm_s[pos] = dinv[r] * dinv[c];
    }
}

// ---------------------------------------------------------------------------
// W convert: W[K=256][Nout] fp32 -> B3 [Nout][768] fp16, layout [Wh | Wl | Wh]
// so that A3=[Ah|Ah|Al] x B3=[Bh;Bl;Bh] = Ah*Bh + Ah*Bl + Al*Bh.
// ---------------------------------------------------------------------------
__global__ __launch_bounds__(256) void wconv3_k(const float* __restrict__ W,
                                                _Float16* __restrict__ B3, int Nout) {
    int n = blockIdx.x;            // 0..Nout-1
    int k = threadIdx.x;           // 0..255
    float v = W[(size_t)k * Nout + n];
    _Float16 h = (_Float16)v;
    _Float16 l = (_Float16)(v - (float)h);
    B3[(size_t)n * 768 + k]       = h;
    B3[(size_t)n * 768 + 256 + k] = l;
    B3[(size_t)n * 768 + 512 + k] = h;
}

// ---------------------------------------------------------------------------
// Single-pass fp16 MFMA GEMM over virtual K=768 (m97 structure):
// C[M,Nout] = A3[M,768] @ B3^T, A3 = [Ah | Ah | Al] (segment-selected staging).
// Block 128x128, 4 waves (2x2), wave tile 64x64, mfma_f32_16x16x32_f16,
// global_load_lds width-16 staging into linear LDS [128][32].
// ---------------------------------------------------------------------------
__device__ __forceinline__ void gload_lds16(const void* g, void* l) {
    __builtin_amdgcn_global_load_lds(
        (const __attribute__((address_space(1))) void*)g,
        (__attribute__((address_space(3))) void*)l, 16, 0, 0);
}

__global__ __launch_bounds__(256) void gemm_f16_k(const _Float16* __restrict__ Ah,
                                                  const _Float16* __restrict__ Al,
                                                  const _Float16* __restrict__ B3,
                                                  float* __restrict__ C,
                                                  int M, int Nout) {
    __shared__ alignas(16) _Float16 sA[128 * 32];   // linear: row r at r*32, 64B rows
    __shared__ alignas(16) _Float16 sB[128 * 32];
    const int K1 = 256;

    int tid = threadIdx.x;
    int row0 = blockIdx.y * 128, col0 = blockIdx.x * 128;
    int wid = tid >> 6, lane = tid & 63;
    int wm = wid >> 1, wn = wid & 1;
    int fr = lane & 15;
    int kb = (lane >> 4) * 8;       // k element base within 32

    // staging mapping: chunk ch covers rows [ch*16, ch*16+16); lane -> row
    // ch*16+(lane>>2), elem (lane&3)*8.  LDS offset == chunkbase + lane*16 (linear).
    int sr = lane >> 2;
    int ke = (lane & 3) * 8;

    f32x4 acc[4][4] = {};

    for (int s = 0; s < 24; ++s) {
        int seg = s >> 3;                 // 0: Ah, 1: Ah (L2-hot), 2: Al
        int k0 = (s & 7) * 32;
        const _Float16* Asrc = (seg == 2) ? Al : Ah;

        __syncthreads();                  // LDS reuse: prior reads done
        #pragma unroll
        for (int c = 0; c < 2; ++c) {
            int ch = wid * 2 + c;         // 0..7
            int r = ch * 16 + sr;
            int arow = row0 + r;
            if (arow < M)
                gload_lds16(&Asrc[(size_t)arow * K1 + k0 + ke], &sA[ch * 512]);
            gload_lds16(&B3[(size_t)(col0 + r) * 768 + s * 32 + ke], &sB[ch * 512]);
        }
        __syncthreads();                  // drains vmcnt (global_load_lds) too

        f16x8 af[4];
        #pragma unroll
        for (int f = 0; f < 4; ++f)
            af[f] = *(const f16x8*)&sA[(wm * 64 + f * 16 + fr) * 32 + kb];
        #pragma unroll
        for (int g = 0; g < 4; ++g) {
            f16x8 bf_ = *(const f16x8*)&sB[(wn * 64 + g * 16 + fr) * 32 + kb];
            #pragma unroll
            for (int f = 0; f < 4; ++f)
                acc[f][g] = __builtin_amdgcn_mfma_f32_16x16x32_f16(af[f], bf_, acc[f][g], 0, 0, 0);
        }
    }

    int rsub = (lane >> 4) * 4;
    #pragma unroll
    for (int f = 0; f < 4; ++f) {
        #pragma unroll
        for (int g = 0; g < 4; ++g) {
            int col = col0 + wn * 64 + g * 16 + fr;
            #pragma unroll
            for (int r = 0; r < 4; ++r) {
                int row = row0 + wm * 64 + f * 16 + rsub + r;
                if (row < M) C[(size_t)row * Nout + col] = acc[f][g][r];
            }
        }
    }
}

// ---------------------------------------------------------------------------
// Aggregation, one wave per node, edge loop unrolled x4.
// MODE 0: relu, write fp16 hi/lo split (feeds next GEMM)
// MODE 1: no relu, write fp32 (final output)
// ---------------------------------------------------------------------------
template <int D, int MODE>
__global__ __launch_bounds__(256) void aggregate_k(const float* __restrict__ H,
                                                   const float* __restrict__ bias,
                                                   const float* __restrict__ dinv,
                                                   const int* __restrict__ rp,
                                                   const int* __restrict__ cs,
                                                   const float* __restrict__ ns,
                                                   _Float16* __restrict__ Yh,
                                                   _Float16* __restrict__ Yl,
                                                   float* __restrict__ Yf, int n) {
    constexpr int VEC = D / 64;
    int v = blockIdx.x * 4 + (threadIdx.x >> 6);
    if (v >= n) return;
    int lane = threadIdx.x & 63;
    float dv = dinv[v];
    float self = dv * dv;
    float acc[VEC];
    const float* hv = H + (size_t)v * D + lane * VEC;
    #pragma unroll
    for (int i = 0; i < VEC; ++i) acc[i] = self * hv[i];

    int s = rp[v], e = rp[v + 1];
    int j = s;
    for (; j + 4 <= e; j += 4) {
        int c0 = cs[j], c1 = cs[j + 1], c2 = cs[j + 2], c3 = cs[j + 3];
        float n0 = ns[j], n1 = ns[j + 1], n2 = ns[j + 2], n3 = ns[j + 3];
        const float* p0 = H + (size_t)c0 * D + lane * VEC;
        const float* p1 = H + (size_t)c1 * D + lane * VEC;
        const float* p2 = H + (size_t)c2 * D + lane * VEC;
        const float* p3 = H + (size_t)c3 * D + lane * VEC;
        if constexpr (VEC == 4) {
            float4 t0 = *(const float4*)p0, t1 = *(const float4*)p1;
            float4 t2 = *(const float4*)p2, t3 = *(const float4*)p3;
            acc[0] += n0 * t0.x + n1 * t1.x + n2 * t2.x + n3 * t3.x;
            acc[1] += n0 * t0.y + n1 * t1.y + n2 * t2.y + n3 * t3.y;
            acc[2] += n0 * t0.z + n1 * t1.z + n2 * t2.z + n3 * t3.z;
            acc[3] += n0 * t0.w + n1 * t1.w + n2 * t2.w + n3 * t3.w;
        } else {
            float2 t0 = *(const float2*)p0, t1 = *(const float2*)p1;
            float2 t2 = *(const float2*)p2, t3 = *(const float2*)p3;
            acc[0] += n0 * t0.x + n1 * t1.x + n2 * t2.x + n3 * t3.x;
            acc[1] += n0 * t0.y + n1 * t1.y + n2 * t2.y + n3 * t3.y;
        }
    }
    for (; j < e; ++j) {
        int c = cs[j];
        float nm = ns[j];
        const float* hc = H + (size_t)c * D + lane * VEC;
        if constexpr (VEC == 4) {
            float4 t = *(const float4*)hc;
            acc[0] += nm * t.x; acc[1] += nm * t.y; acc[2] += nm * t.z; acc[3] += nm * t.w;
        } else {
            float2 t = *(const float2*)hc;
            acc[0] += nm * t.x; acc[1] += nm * t.y;
        }
    }

    #pragma unroll
    for (int i = 0; i < VEC; ++i) acc[i] += bias[lane * VEC + i];

    if constexpr (MODE == 0) {
        f16x4 hh, ll;
        #pragma unroll
        for (int i = 0; i < VEC; ++i) {
            float o = fmaxf(acc[i], 0.0f);
            _Float16 h = (_Float16)o;
            hh[i] = h;
            ll[i] = (_Float16)(o - (float)h);
        }
        *(f16x4*)&Yh[(size_t)v * D + lane * VEC] = hh;
        *(f16x4*)&Yl[(size_t)v * D + lane * VEC] = ll;
    } else {
        float* yp = Yf + (size_t)v * D + lane * VEC;
        if constexpr (VEC == 4)
            *(float4*)yp = make_float4(acc[0], acc[1], acc[2], acc[3]);
        else
            *(float2*)yp = make_float2(acc[0], acc[1]);
    }
}

// ---------------------------------------------------------------------------
extern "C" void kernel_launch(void* const* d_in, const int* in_sizes, int n_in,
                              void* d_out, int out_size, void* d_ws, size_t ws_size,
                              hipStream_t stream) {
    const float* qe  = (const float*)d_in[0];
    const float* obj = (const float*)d_in[1];
    const void*  edges = d_in[2];
    const float* W1 = (const float*)d_in[3];
    const float* b1 = (const float*)d_in[4];
    const float* W2 = (const float*)d_in[5];
    const float* b2 = (const float*)d_in[6];
    const float* W3 = (const float*)d_in[7];
    const float* b3 = (const float*)d_in[8];
    float* out = (float*)d_out;

    char* p = (char*)d_ws;
    _Float16* Xh   = (_Float16*)p; p += (size_t)NN * 256 * 2;   // 25.6 MB
    _Float16* Xl   = (_Float16*)p; p += (size_t)NN * 256 * 2;   // 25.6 MB
    float* H       = (float*)p;    p += (size_t)NN * 256 * 4;   // 51.2 MB
    _Float16* B3   = (_Float16*)p; p += (size_t)256 * 768 * 2;  // 0.4 MB
    int*   deg     = (int*)p;   p += (size_t)NN * 4;
    float* dinv    = (float*)p; p += (size_t)NN * 4;
    int*   rp      = (int*)p;   p += (size_t)(NN + 1) * 4;
    int*   cursor  = (int*)p;   p += (size_t)NN * 4;
    int*   col_s   = (int*)p;   p += (size_t)NE * 4;
    float* norm_s  = (float*)p; p += (size_t)NE * 4;
    int*   flag    = (int*)p;   p += 4;

    zero_flag_k<<<1, 64, 0, stream>>>(flag);
    detect_k<<<4, 256, 0, stream>>>((const int*)edges, flag);
    hadamard_k<<<(NN * 64 + 255) / 256, 256, 0, stream>>>(
        (const float4*)qe, (const float4*)obj, Xh, Xl, NN * 64);
    init_k<<<(NN + 255) / 256, 256, 0, stream>>>(deg, cursor, NN);
    count_k<<<(NE + 255) / 256, 256, 0, stream>>>(edges, flag, deg, NE);
    dinv_k<<<(NN + 255) / 256, 256, 0, stream>>>(deg, dinv, NN);
    scan_k<<<1, 1024, 0, stream>>>(deg, rp, NN);
    scatter_k<<<(NE + 255) / 256, 256, 0, stream>>>(edges, flag, dinv, rp, cursor,
                                                    col_s, norm_s, NE);

    int mblk = (NN + 127) / 128;            // 391
    int aggGrid = (NN + 3) / 4;

    // Layer 1
    wconv3_k<<<256, 256, 0, stream>>>(W1, B3, 256);
    gemm_f16_k<<<dim3(2, mblk), 256, 0, stream>>>(Xh, Xl, B3, H, NN, 256);
    aggregate_k<256, 0><<<aggGrid, 256, 0, stream>>>(H, b1, dinv, rp, col_s, norm_s,
                                                     Xh, Xl, nullptr, NN);
    // Layer 2
    wconv3_k<<<256, 256, 0, stream>>>(W2, B3, 256);
    gemm_f16_k<<<dim3(2, mblk), 256, 0, stream>>>(Xh, Xl, B3, H, NN, 256);
    aggregate_k<256, 0><<<aggGrid, 256, 0, stream>>>(H, b2, dinv, rp, col_s, norm_s,
                                                     Xh, Xl, nullptr, NN);
    // Layer 3
    wconv3_k<<<128, 256, 0, stream>>>(W3, B3, 128);
    gemm_f16_k<<<dim3(1, mblk), 256, 0, stream>>>(Xh, Xl, B3, H, NN, 128);
    aggregate_k<128, 1><<<aggGrid, 256, 0, stream>>>(H, b3, dinv, rp, col_s, norm_s,
                                                     nullptr, nullptr, out, NN);
}